// Round 1
// baseline (3945.347 us; speedup 1.0000x reference)
//
#include <hip/hip_runtime.h>

// Problem constants (from reference setup_inputs / module hyper-params)
constexpr int B_N = 4;
constexpr int C_N = 3;
constexpr int H_IMG = 720;
constexpr int W_IMG = 1280;
constexpr int HW = H_IMG * W_IMG;
constexpr int R = 4;            // KERNEL_RADIUS
// KERNEL_SIGMA2 = 0.5 -> weight = exp(-d2 / (2*0.5)) = exp(-d2)

// Tiling
constexpr int TS = 32;          // source tile side
constexpr int HALO = 8;         // covers |floor(flow)| <= 4 + R for interior pixels
constexpr int COV = TS + 2 * HALO;   // 48
constexpr int PLANE = COV * COV;     // 2304 floats per plane
constexpr int TILES_X = W_IMG / TS;                  // 40
constexpr int TILES_Y = (H_IMG + TS - 1) / TS;       // 23

__global__ __launch_bounds__(256, 4)
void splat_kernel(const float* __restrict__ src, const float* __restrict__ flow,
                  float* __restrict__ out) {
    // 4 SoA planes: [w][w*s0][w*s1][w*s2], 48x48 each = 36,864 B
    __shared__ float lds[4 * PLANE];

    const int tile = blockIdx.x;
    const int b = blockIdx.y;
    const int tX0 = (tile % TILES_X) * TS;
    const int tY0 = (tile / TILES_X) * TS;
    const int covx0 = tX0 - HALO;
    const int covy0 = tY0 - HALO;

    for (int i = threadIdx.x; i < 4 * PLANE; i += 256) lds[i] = 0.f;
    __syncthreads();

    float* __restrict__ wI = out;                      // (B,C,H,W)
    float* __restrict__ wb = out + B_N * C_N * HW;     // (B,1,H,W) mask region used as w-acc

    const int xl = threadIdx.x & 31;
    const int yl0 = threadIdx.x >> 5;                  // 0..7
    const float* __restrict__ up = flow + (b * 2) * HW;
    const float* __restrict__ vp = up + HW;
    const float* __restrict__ sp = src + (b * 3) * HW;

    for (int k = 0; k < 4; ++k) {
        const int yl = yl0 + k * 8;
        const int x = tX0 + xl;
        const int y = tY0 + yl;
        if (y >= H_IMG) continue;                      // partial bottom tile row
        const int pix = y * W_IMG + x;
        const float u = up[pix], v = vp[pix];
        const float s0 = sp[pix], s1 = sp[HW + pix], s2 = sp[2 * HW + pix];
        const float px = (float)x + u;
        const float py = (float)y + v;
        const float bxf = floorf(px), byf = floorf(py);
        const int bx = (int)bxf, by = (int)byf;
        const float fu = px - bxf;                     // in [0,1)
        const float fv = py - byf;

        // Separable x-weights: d = dx - fu, dx in [-4,4]
        float sx[9], wx[9];
#pragma unroll
        for (int i = 0; i < 9; ++i) {
            const float d = (float)(i - R) - fu;
            sx[i] = d * d;
            wx[i] = __expf(-d * d);
        }

        const bool fast = (bx - R >= covx0) && (bx + R < covx0 + COV) &&
                          (by - R >= covy0) && (by + R < covy0 + COV);
        if (__builtin_expect(fast, 1)) {
            const int lx0 = bx - R - covx0;
#pragma unroll
            for (int j = 0; j < 9; ++j) {
                const float dyf = (float)(j - R) - fv;
                const float sy = dyf * dyf;
                const float wy = __expf(-sy);
                const int lb = (by + j - R - covy0) * COV + lx0;
#pragma unroll
                for (int i = 0; i < 9; ++i) {
                    const float d2 = sy + sx[i];
                    if (d2 <= 16.0f) {                 // circular cutoff (R*R)
                        const float w = wy * wx[i];
                        const int a = lb + i;
                        atomicAdd(&lds[a], w);
                        atomicAdd(&lds[a + PLANE], w * s0);
                        atomicAdd(&lds[a + 2 * PLANE], w * s1);
                        atomicAdd(&lds[a + 3 * PLANE], w * s2);
                    }
                }
            }
            // Note: targets outside the image land in LDS cells that are never
            // flushed (flush is bounds-checked), matching reference w=0 there.
        } else {
            // Rare (P ~ 6e-5): |flow| large near tile edge — direct global atomics
            for (int j = 0; j < 9; ++j) {
                const int ty = by + j - R;
                if (ty < 0 || ty >= H_IMG) continue;
                const float dyf = (float)(j - R) - fv;
                const float sy = dyf * dyf;
                const float wy = __expf(-sy);
                for (int i = 0; i < 9; ++i) {
                    const int tx = bx + i - R;
                    if (tx < 0 || tx >= W_IMG) continue;
                    const float d2 = sy + sx[i];
                    if (d2 > 16.0f) continue;
                    const float w = wy * wx[i];
                    const int t = ty * W_IMG + tx;
                    atomicAdd(&wb[b * HW + t], w);
                    atomicAdd(&wI[(b * 3 + 0) * HW + t], w * s0);
                    atomicAdd(&wI[(b * 3 + 1) * HW + t], w * s1);
                    atomicAdd(&wI[(b * 3 + 2) * HW + t], w * s2);
                }
            }
        }
    }

    __syncthreads();

    // Flush LDS coverage to global accumulators (halo overlaps neighbors -> atomics)
    for (int i = threadIdx.x; i < PLANE; i += 256) {
        const int gx = covx0 + (i % COV);
        const int gy = covy0 + (i / COV);
        if (gx < 0 || gx >= W_IMG || gy < 0 || gy >= H_IMG) continue;
        const float w = lds[i];
        if (w == 0.f) continue;    // w==0 implies all wI contributions were 0 too
        const int t = gy * W_IMG + gx;
        atomicAdd(&wb[b * HW + t], w);
        atomicAdd(&wI[(b * 3 + 0) * HW + t], lds[i + PLANE]);
        atomicAdd(&wI[(b * 3 + 1) * HW + t], lds[i + 2 * PLANE]);
        atomicAdd(&wI[(b * 3 + 2) * HW + t], lds[i + 3 * PLANE]);
    }
}

__global__ __launch_bounds__(256)
void finalize_kernel(float* __restrict__ out) {
    const int i = blockIdx.x * blockDim.x + threadIdx.x;
    if (i >= B_N * HW) return;
    float* __restrict__ wb = out + B_N * C_N * HW;
    const float w = wb[i];
    const float inv = 1.0f / (w + 1e-8f);
    const int b = i / HW;
    const int hw = i - b * HW;
    const int base = (b * 3) * HW + hw;
    out[base] *= inv;
    out[base + HW] *= inv;
    out[base + 2 * HW] *= inv;
    wb[i] = (w > 0.f) ? 1.f : 0.f;
}

extern "C" void kernel_launch(void* const* d_in, const int* in_sizes, int n_in,
                              void* d_out, int out_size, void* d_ws, size_t ws_size,
                              hipStream_t stream) {
    const float* src = (const float*)d_in[0];    // (4,3,720,1280) fp32
    const float* flow = (const float*)d_in[1];   // (4,2,720,1280) fp32
    float* out = (float*)d_out;                  // img (4,3,HW) ++ mask (4,1,HW)

    // d_out is poisoned 0xAA before every timed launch — zero our accumulators.
    hipMemsetAsync(d_out, 0, (size_t)out_size * sizeof(float), stream);

    dim3 grid(TILES_X * TILES_Y, B_N);
    splat_kernel<<<grid, 256, 0, stream>>>(src, flow, out);

    const int n = B_N * HW;
    finalize_kernel<<<(n + 255) / 256, 256, 0, stream>>>(out);
}

// Round 2
// 517.334 us; speedup vs baseline: 7.6263x; 7.6263x over previous
//
#include <hip/hip_runtime.h>

// Problem constants
constexpr int B_N = 4;
constexpr int C_N = 3;
constexpr int H_IMG = 720;
constexpr int W_IMG = 1280;
constexpr int HW = H_IMG * W_IMG;
// KERNEL_RADIUS=4, KERNEL_SIGMA2=0.5 -> w = exp(-d2)

// Gather tiling: block owns 64x32 targets; thread owns 8 consecutive x.
constexpr int TW = 64, TH = 32;
constexpr int HALO = 8;                 // R + flow slack (4+4)
constexpr int CW = TW + 2 * HALO;       // 80
constexpr int CH = TH + 2 * HALO;       // 48
constexpr int PITCH = CW + 1;           // 81: (81*r + 8*xg) mod 32 -> 2-way max (free)
constexpr int PLANE = CH * PITCH;       // 3888 floats/plane
constexpr float FLOW_MAX = 4.0f;        // outlier threshold (slack = HALO - R)

// e^{-1}, e^{-3}, e^{-5}, e^{-7} for the G^delta recurrence
#define K1 0.36787944117144233f
#define K3 0.049787068367863944f
#define K5 0.006737946999085467f
#define K7 0.0009118819655545162f

__global__ __launch_bounds__(256, 2)
void gather_kernel(const float* __restrict__ src, const float* __restrict__ flow,
                   float* __restrict__ out) {
    __shared__ float PX[PLANE], PY[PLANE], S0[PLANE], S1[PLANE], S2[PLANE];

    const int b = blockIdx.z;
    const int tx0 = blockIdx.x * TW;
    const int ty0 = blockIdx.y * TH;
    const int cx0 = tx0 - HALO, cy0 = ty0 - HALO;

    const float* __restrict__ up = flow + (size_t)(b * 2) * HW;
    const float* __restrict__ vp = up + HW;
    const float* __restrict__ sp = src + (size_t)(b * 3) * HW;

    // Stage coverage: continuous landing pos + channels. Invalid / outlier
    // cells get px=py=1e6 (clamped later -> exp underflows to 0) and s=0.
    for (int idx = threadIdx.x; idx < CH * CW; idx += 256) {
        const int cy = idx / CW, cx = idx - cy * CW;
        const int gx = cx0 + cx, gy = cy0 + cy;
        float px = 1.0e6f, py = 1.0e6f, s0 = 0.f, s1 = 0.f, s2 = 0.f;
        if (gx >= 0 && gx < W_IMG && gy >= 0 && gy < H_IMG) {
            const int g = gy * W_IMG + gx;
            const float u = up[g], v = vp[g];
            if (fabsf(u) <= FLOW_MAX && fabsf(v) <= FLOW_MAX) {  // outliers -> scatter kernel
                px = (float)gx + u;
                py = (float)gy + v;
                s0 = sp[g]; s1 = sp[HW + g]; s2 = sp[2 * HW + g];
            }
        }
        const int l = cy * PITCH + cx;
        PX[l] = px; PY[l] = py; S0[l] = s0; S1[l] = s1; S2[l] = s2;
    }
    __syncthreads();

    const int xg = threadIdx.x & 7;     // 8 column groups
    const int rL = threadIdx.x >> 3;    // 32 rows
    const int ty = ty0 + rL;
    if (ty >= H_IMG) return;            // partial bottom tile; no barriers follow

    const float tyf = (float)ty;
    const float txcf = (float)(tx0 + 8 * xg + 4);   // center target (i=4)

    float accw[8], a0[8], a1[8], a2[8];
#pragma unroll
    for (int i = 0; i < 8; ++i) { accw[i] = 0.f; a0[i] = 0.f; a1[i] = 0.f; a2[i] = 0.f; }

    for (int oy = 0; oy < 17; ++oy) {
        const int base = (rL + oy) * PITCH + 8 * xg;
        for (int ox = 0; ox < 24; ++ox) {
            const int l = base + ox;
            const float px = PX[l], py = PY[l];
            const float s0 = S0[l], s1 = S1[l], s2 = S2[l];

            float dy = py - tyf;
            dy = fminf(fmaxf(dy, -30.f), 30.f);
            const float ey = __expf(-dy * dy);

            float dx = px - txcf;
            dx = fminf(fmaxf(dx, -30.f), 30.f);
            // w(delta) = exp(-(dx-delta)^2) = E * G^delta * e^{-delta^2}
            const float E = __expf(-dx * dx);
            const float G = __expf(dx + dx);
            const float Gi = __expf(-(dx + dx));
            const float m1 = G * K1, m3 = G * K3, m5 = G * K5;
            const float n1 = Gi * K1, n3 = Gi * K3, n5 = Gi * K5, n7 = Gi * K7;

            float w[8];
            w[4] = E;
            w[5] = w[4] * m1; w[6] = w[5] * m3; w[7] = w[6] * m5;
            w[3] = w[4] * n1; w[2] = w[3] * n3; w[1] = w[2] * n5; w[0] = w[1] * n7;

#pragma unroll
            for (int i = 0; i < 8; ++i) {
                const float wt = w[i] * ey;
                accw[i] += wt;
                a0[i] = fmaf(wt, s0, a0[i]);
                a1[i] = fmaf(wt, s1, a1[i]);
                a2[i] = fmaf(wt, s2, a2[i]);
            }
        }
    }

    // Write raw accumulators; outlier scatter adds, finalize divides.
    float* __restrict__ wI = out;
    float* __restrict__ wb = out + (size_t)B_N * C_N * HW;
    const int tbase = ty * W_IMG + tx0 + 8 * xg;
#pragma unroll
    for (int i = 0; i < 8; ++i) {
        const int t = tbase + i;
        wI[(size_t)(b * 3 + 0) * HW + t] = a0[i];
        wI[(size_t)(b * 3 + 1) * HW + t] = a1[i];
        wI[(size_t)(b * 3 + 2) * HW + t] = a2[i];
        wb[(size_t)b * HW + t] = accw[i];
    }
}

// Exact splat for rare sources with |u|>4 or |v|>4 (P ~ 6e-5 each comp).
__global__ __launch_bounds__(256)
void outlier_kernel(const float* __restrict__ src, const float* __restrict__ flow,
                    float* __restrict__ out) {
    const int i = blockIdx.x * 256 + threadIdx.x;
    if (i >= B_N * HW) return;
    const int b = i / HW, g = i - b * HW;
    const float* __restrict__ up = flow + (size_t)(b * 2) * HW;
    const float u = up[g], v = up[HW + g];
    if (fabsf(u) <= FLOW_MAX && fabsf(v) <= FLOW_MAX) return;

    const int x = g % W_IMG, y = g / W_IMG;
    const float px = (float)x + u, py = (float)y + v;
    if (!(px > -6.f && px < (float)W_IMG + 5.f &&
          py > -6.f && py < (float)H_IMG + 5.f)) return;

    const float bxf = floorf(px), byf = floorf(py);
    const int bx = (int)bxf, by = (int)byf;
    const float* __restrict__ sp = src + (size_t)(b * 3) * HW;
    const float s0 = sp[g], s1 = sp[HW + g], s2 = sp[2 * HW + g];
    float* __restrict__ wI = out;
    float* __restrict__ wb = out + (size_t)B_N * C_N * HW;

    for (int dyi = -4; dyi <= 4; ++dyi) {
        const int tyy = by + dyi;
        if (tyy < 0 || tyy >= H_IMG) continue;
        const float dyf = (byf + (float)dyi) - py;
        const float dy2 = dyf * dyf;
        for (int dxi = -4; dxi <= 4; ++dxi) {
            const int txx = bx + dxi;
            if (txx < 0 || txx >= W_IMG) continue;
            const float dxf = (bxf + (float)dxi) - px;
            const float d2 = fmaf(dxf, dxf, dy2);
            if (d2 > 16.f) continue;
            const float w = __expf(-d2);
            const int t = tyy * W_IMG + txx;
            atomicAdd(&wb[(size_t)b * HW + t], w);
            atomicAdd(&wI[(size_t)(b * 3 + 0) * HW + t], w * s0);
            atomicAdd(&wI[(size_t)(b * 3 + 1) * HW + t], w * s1);
            atomicAdd(&wI[(size_t)(b * 3 + 2) * HW + t], w * s2);
        }
    }
}

__global__ __launch_bounds__(256)
void finalize_kernel(float* __restrict__ out) {
    const int i = blockIdx.x * blockDim.x + threadIdx.x;
    if (i >= B_N * HW) return;
    float* __restrict__ wb = out + (size_t)B_N * C_N * HW;
    const float w = wb[i];
    const float inv = 1.0f / (w + 1e-8f);
    const int b = i / HW;
    const int hw = i - b * HW;
    const size_t base = (size_t)(b * 3) * HW + hw;
    out[base] *= inv;
    out[base + HW] *= inv;
    out[base + 2 * (size_t)HW] *= inv;
    wb[i] = (w > 0.f) ? 1.f : 0.f;
}

extern "C" void kernel_launch(void* const* d_in, const int* in_sizes, int n_in,
                              void* d_out, int out_size, void* d_ws, size_t ws_size,
                              hipStream_t stream) {
    const float* src = (const float*)d_in[0];    // (4,3,720,1280) fp32
    const float* flow = (const float*)d_in[1];   // (4,2,720,1280) fp32
    float* out = (float*)d_out;                  // img (4,3,HW) ++ mask (4,1,HW)

    // gather writes every output cell -> no memset needed.
    dim3 grid(W_IMG / TW, (H_IMG + TH - 1) / TH, B_N);   // 20 x 23 x 4
    gather_kernel<<<grid, 256, 0, stream>>>(src, flow, out);

    const int n = B_N * HW;
    outlier_kernel<<<(n + 255) / 256, 256, 0, stream>>>(src, flow, out);
    finalize_kernel<<<(n + 255) / 256, 256, 0, stream>>>(out);
}

// Round 3
// 440.534 us; speedup vs baseline: 8.9558x; 1.1743x over previous
//
#include <hip/hip_runtime.h>
#include <hip/hip_fp16.h>

// Problem constants
constexpr int B_N = 4;
constexpr int C_N = 3;
constexpr int H_IMG = 720;
constexpr int W_IMG = 1280;
constexpr int HW = H_IMG * W_IMG;
// KERNEL_RADIUS=4, KERNEL_SIGMA2=0.5 -> w = exp(-d2)

// Gather tiling: block owns 64x32 targets; thread owns 8 consecutive x.
constexpr int TW = 64, TH = 32;
constexpr int HALO = 8;                 // R + flow slack (4+4)
constexpr int CW = TW + 2 * HALO;       // 80
constexpr int CH = TH + 2 * HALO;       // 48
constexpr int PITCH = CW + 1;           // 81: 2-way max bank aliasing (free)
constexpr int PLANE = CH * PITCH;       // 3888 words/plane; 3 planes = 46.7 KB
constexpr float FLOW_MAX = 4.0f;        // outlier threshold (halo slack)
constexpr float LOG2E = 1.44269504f;

// e^{-1}, e^{-3}, e^{-5}, e^{-7} for the G^delta recurrence
#define K1 0.36787944117144233f
#define K3 0.049787068367863944f
#define K5 0.006737946999085467f
#define K7 0.0009118819655545162f

typedef float v2f __attribute__((ext_vector_type(2)));
static __device__ __forceinline__ v2f splat2(float x) { return (v2f){x, x}; }

__global__ __launch_bounds__(256, 3)
void gather_kernel(const float* __restrict__ src, const float* __restrict__ flow,
                   float* __restrict__ out) {
    __shared__ __half2 UV[PLANE];     // (u, v) per source cell
    __shared__ __half2 S01[PLANE];    // (s0, s1)
    __shared__ float   S2[PLANE];     // s2

    const int b = blockIdx.z;
    const int tx0 = blockIdx.x * TW;
    const int ty0 = blockIdx.y * TH;
    const int cx0 = tx0 - HALO, cy0 = ty0 - HALO;

    const float* __restrict__ up = flow + (size_t)(b * 2) * HW;
    const float* __restrict__ vp = up + HW;
    const float* __restrict__ sp = src + (size_t)(b * 3) * HW;

    // Stage coverage. Invalid / outlier cells get u=v=300 (range-check fails).
    for (int idx = threadIdx.x; idx < CH * CW; idx += 256) {
        const int cy = idx / CW, cx = idx - cy * CW;
        const int gx = cx0 + cx, gy = cy0 + cy;
        float u = 300.f, v = 300.f, s0 = 0.f, s1 = 0.f, s2 = 0.f;
        if (gx >= 0 && gx < W_IMG && gy >= 0 && gy < H_IMG) {
            const int g = gy * W_IMG + gx;
            const float uu = up[g], vv = vp[g];
            if (fabsf(uu) <= FLOW_MAX && fabsf(vv) <= FLOW_MAX) {  // outliers -> scatter kernel
                u = uu; v = vv;
                s0 = sp[g]; s1 = sp[HW + g]; s2 = sp[2 * HW + g];
            }
        }
        const int l = cy * PITCH + cx;
        UV[l] = __floats2half2_rn(u, v);
        S01[l] = __floats2half2_rn(s0, s1);
        S2[l] = s2;
    }
    __syncthreads();

    const int xg = threadIdx.x & 7;     // 8 column groups of 8 targets
    const int rL = threadIdx.x >> 3;    // 32 rows
    const int ty = ty0 + rL;
    if (ty >= H_IMG) return;            // partial bottom tile; no barriers follow

    v2f AW[4], A0[4], A1[4], A2[4];
#pragma unroll
    for (int k = 0; k < 4; ++k) { AW[k] = splat2(0.f); A0[k] = splat2(0.f);
                                  A1[k] = splat2(0.f); A2[k] = splat2(0.f); }

    for (int oy = 0; oy < 17; ++oy) {
        const float Cy = (float)(oy - 8);
        const int rowbase = (rL + oy) * PITCH + 8 * xg;
#pragma unroll
        for (int ox = 0; ox < 24; ++ox) {
            const int l = rowbase + ox;
            const float2 uv = __half22float2(UV[l]);
            // dx = px - group_center_x ; dy = py - ty (lane-uniform constants)
            const float dx = uv.x + (float)(ox - 12);
            const float dy = uv.y + Cy;
            const float dxL = dx * LOG2E;
            const float tX = dx * dxL;          // dx^2 * log2(e)
            const float dyL = dy * LOG2E;
            const float tY = dy * dyL;
            // In-range: |dx|<8.83, |dy|<5.01 (else all 8 weights < e^-23)
            if (tX < 112.6f && tY < 36.2f) {
                const float E = __builtin_amdgcn_exp2f(-tX);   // exp(-dx^2)
                const float g = dxL + dxL;
                const float G = __builtin_amdgcn_exp2f(g);     // exp(2dx)
                const float Gi = __builtin_amdgcn_exp2f(-g);   // exp(-2dx)
                const float ey = __builtin_amdgcn_exp2f(-tY);  // exp(-dy^2)

                const float m1 = G * K1, m3 = G * K3, m5 = G * K5;
                const float n1 = Gi * K1, n3 = Gi * K3, n5 = Gi * K5, n7 = Gi * K7;
                // w[i] = exp(-(dx - (i-4))^2), chained from center
                const float w4 = E;
                const float w5 = w4 * m1, w6 = w5 * m3, w7 = w6 * m5;
                const float w3 = w4 * n1, w2 = w3 * n3, w1 = w2 * n5, w0 = w1 * n7;

                const float2 s01 = __half22float2(S01[l]);
                const float s2v = S2[l];
                const v2f ey2 = splat2(ey);
                const v2f s0s = splat2(s01.x), s1s = splat2(s01.y), s2s = splat2(s2v);

                v2f W[4];
                W[0] = (v2f){w0, w1}; W[1] = (v2f){w2, w3};
                W[2] = (v2f){w4, w5}; W[3] = (v2f){w6, w7};
#pragma unroll
                for (int k = 0; k < 4; ++k) {
                    const v2f wt = W[k] * ey2;
                    AW[k] += wt;
                    A0[k] = __builtin_elementwise_fma(wt, s0s, A0[k]);
                    A1[k] = __builtin_elementwise_fma(wt, s1s, A1[k]);
                    A2[k] = __builtin_elementwise_fma(wt, s2s, A2[k]);
                }
            }
        }
    }

    // Write raw accumulators (float4); outlier scatter adds, finalize divides.
    float* __restrict__ wI = out;
    float* __restrict__ wb = out + (size_t)B_N * C_N * HW;
    const int tb = ty * W_IMG + tx0 + 8 * xg;     // 16B-aligned
    float* p0 = wI + (size_t)(b * 3 + 0) * HW + tb;
    float* p1 = wI + (size_t)(b * 3 + 1) * HW + tb;
    float* p2 = wI + (size_t)(b * 3 + 2) * HW + tb;
    float* pw = wb + (size_t)b * HW + tb;
    *(float4*)(p0)     = make_float4(A0[0].x, A0[0].y, A0[1].x, A0[1].y);
    *(float4*)(p0 + 4) = make_float4(A0[2].x, A0[2].y, A0[3].x, A0[3].y);
    *(float4*)(p1)     = make_float4(A1[0].x, A1[0].y, A1[1].x, A1[1].y);
    *(float4*)(p1 + 4) = make_float4(A1[2].x, A1[2].y, A1[3].x, A1[3].y);
    *(float4*)(p2)     = make_float4(A2[0].x, A2[0].y, A2[1].x, A2[1].y);
    *(float4*)(p2 + 4) = make_float4(A2[2].x, A2[2].y, A2[3].x, A2[3].y);
    *(float4*)(pw)     = make_float4(AW[0].x, AW[0].y, AW[1].x, AW[1].y);
    *(float4*)(pw + 4) = make_float4(AW[2].x, AW[2].y, AW[3].x, AW[3].y);
}

// Exact splat for rare sources with |u|>4 or |v|>4 (P ~ 1.2e-4 total).
__global__ __launch_bounds__(256)
void outlier_kernel(const float* __restrict__ src, const float* __restrict__ flow,
                    float* __restrict__ out) {
    const int i = blockIdx.x * 256 + threadIdx.x;
    if (i >= B_N * HW) return;
    const int b = i / HW, g = i - b * HW;
    const float* __restrict__ up = flow + (size_t)(b * 2) * HW;
    const float u = up[g], v = up[HW + g];
    if (fabsf(u) <= FLOW_MAX && fabsf(v) <= FLOW_MAX) return;

    const int x = g % W_IMG, y = g / W_IMG;
    const float px = (float)x + u, py = (float)y + v;
    if (!(px > -6.f && px < (float)W_IMG + 5.f &&
          py > -6.f && py < (float)H_IMG + 5.f)) return;

    const float bxf = floorf(px), byf = floorf(py);
    const int bx = (int)bxf, by = (int)byf;
    const float* __restrict__ sp = src + (size_t)(b * 3) * HW;
    const float s0 = sp[g], s1 = sp[HW + g], s2 = sp[2 * HW + g];
    float* __restrict__ wI = out;
    float* __restrict__ wb = out + (size_t)B_N * C_N * HW;

    for (int dyi = -4; dyi <= 4; ++dyi) {
        const int tyy = by + dyi;
        if (tyy < 0 || tyy >= H_IMG) continue;
        const float dyf = (byf + (float)dyi) - py;
        const float dy2 = dyf * dyf;
        for (int dxi = -4; dxi <= 4; ++dxi) {
            const int txx = bx + dxi;
            if (txx < 0 || txx >= W_IMG) continue;
            const float dxf = (bxf + (float)dxi) - px;
            const float d2 = fmaf(dxf, dxf, dy2);
            if (d2 > 16.f) continue;
            const float w = __expf(-d2);
            const int t = tyy * W_IMG + txx;
            atomicAdd(&wb[(size_t)b * HW + t], w);
            atomicAdd(&wI[(size_t)(b * 3 + 0) * HW + t], w * s0);
            atomicAdd(&wI[(size_t)(b * 3 + 1) * HW + t], w * s1);
            atomicAdd(&wI[(size_t)(b * 3 + 2) * HW + t], w * s2);
        }
    }
}

__global__ __launch_bounds__(256)
void finalize_kernel(float* __restrict__ out) {
    const int i = blockIdx.x * blockDim.x + threadIdx.x;
    const int n4 = B_N * HW / 4;
    if (i >= n4) return;
    const int per_b = HW / 4;
    const int b = i / per_b;
    const int hw = (i - b * per_b) * 4;
    float* __restrict__ wb = out + (size_t)B_N * C_N * HW + (size_t)b * HW + hw;
    float4 w = *(float4*)wb;
    const float4 inv = make_float4(1.f / (w.x + 1e-8f), 1.f / (w.y + 1e-8f),
                                   1.f / (w.z + 1e-8f), 1.f / (w.w + 1e-8f));
    float* base = out + (size_t)(b * 3) * HW + hw;
#pragma unroll
    for (int c = 0; c < 3; ++c) {
        float4 t = *(float4*)(base + (size_t)c * HW);
        t.x *= inv.x; t.y *= inv.y; t.z *= inv.z; t.w *= inv.w;
        *(float4*)(base + (size_t)c * HW) = t;
    }
    *(float4*)wb = make_float4(w.x > 0.f ? 1.f : 0.f, w.y > 0.f ? 1.f : 0.f,
                               w.z > 0.f ? 1.f : 0.f, w.w > 0.f ? 1.f : 0.f);
}

extern "C" void kernel_launch(void* const* d_in, const int* in_sizes, int n_in,
                              void* d_out, int out_size, void* d_ws, size_t ws_size,
                              hipStream_t stream) {
    const float* src = (const float*)d_in[0];    // (4,3,720,1280) fp32
    const float* flow = (const float*)d_in[1];   // (4,2,720,1280) fp32
    float* out = (float*)d_out;                  // img (4,3,HW) ++ mask (4,1,HW)

    dim3 grid(W_IMG / TW, (H_IMG + TH - 1) / TH, B_N);   // 20 x 23 x 4
    gather_kernel<<<grid, 256, 0, stream>>>(src, flow, out);

    const int n = B_N * HW;
    outlier_kernel<<<(n + 255) / 256, 256, 0, stream>>>(src, flow, out);
    const int n4 = n / 4;
    finalize_kernel<<<(n4 + 255) / 256, 256, 0, stream>>>(out);
}